// Round 11
// baseline (1654.803 us; speedup 1.0000x reference)
//
#include <hip/hip_runtime.h>

#define NB 8
#define NN 2048
#define MM 2048
#define DD 64
#define NMAT ((size_t)NN * (size_t)MM)
#define NCHK 16
#define TS 128

typedef _Float16 half_t;
typedef __attribute__((ext_vector_type(8))) _Float16 f16x8;
typedef __attribute__((ext_vector_type(4))) float f32x4;

// ---------------------------------------------------------------------------
// Static device scratch. NO materialized cost matrices anymore — tiles are
// recomputed on the fly by MFMA inside tile_pass (x,y fp16 = 4 MB, L2-hot).
// ---------------------------------------------------------------------------
__device__ half_t g_xh[NB * NN * DD];           // fp16 copies for MFMA
__device__ half_t g_yh[NB * MM * DD];
// potential banks: [0]/[1] = carry double-buffer, [2] = final
__device__ float g_fab[3][NB * NN], g_gba[3][NB * NN];
__device__ float g_faa[3][NB * NN], g_gbb[3][NB * NN];
__device__ float g_alog[NB * NN], g_blog[NB * NN];
__device__ float g_xn[NB * NN], g_yn[NB * NN];
__device__ float g_h0[NB * MM], g_h1[NB * NN], g_h2[NB * NN], g_h3[NB * MM];
// chunked softmin partials (m,s): [b][chunk][row]
__device__ float2 g_pfab[NB * NCHK * NN];
__device__ float2 g_pgba[NB * NCHK * NN];
__device__ float2 g_pfaa[NB * NCHK * NN];
__device__ float2 g_pgbb[NB * NCHK * NN];

// ---------------------------------------------------------------------------
// prep: a_log/b_log = log(w), xn/yn = 0.5*||row||^2, and fp16 copies of x,y.
// ---------------------------------------------------------------------------
__global__ __launch_bounds__(256) void prep_kernel(
    const float* __restrict__ x, const float* __restrict__ y,
    const float* __restrict__ w1, const float* __restrict__ w2)
{
  int gid = blockIdx.x * 256 + threadIdx.x;
  if (gid < NB * NN) {
    g_alog[gid] = logf(w1[gid]);
    g_blog[gid] = logf(w2[gid]);
  }
  int lane = threadIdx.x & 63;
  int row = blockIdx.x * 4 + (threadIdx.x >> 6);   // grid 4096 -> rows 0..16383
  float xv = x[(size_t)row * DD + lane];
  float yv = y[(size_t)row * DD + lane];
  g_xh[(size_t)row * DD + lane] = (half_t)xv;
  g_yh[(size_t)row * DD + lane] = (half_t)yv;
  float sx = xv * xv;
  float sy = yv * yv;
#pragma unroll
  for (int off = 32; off > 0; off >>= 1) {
    sx += __shfl_down(sx, off);
    sy += __shfl_down(sy, off);
  }
  if (lane == 0) {
    g_xn[row] = 0.5f * sx;
    g_yn[row] = 0.5f * sy;
  }
}

// ---------------------------------------------------------------------------
// h-vector prep — used ONCE for the init step (gs = 0); subsequent h's are
// written by merge4.
// ---------------------------------------------------------------------------
__global__ __launch_bounds__(256) void hprep_kernel(
    const float* __restrict__ fab_in, const float* __restrict__ gba_in,
    const float* __restrict__ faa_in, const float* __restrict__ gbb_in,
    float gs)
{
  int i = blockIdx.x * 256 + threadIdx.x;   // grid 64 -> 16384
  g_h0[i] = fmaf(gs, gba_in[i], g_blog[i]);
  g_h1[i] = fmaf(gs, fab_in[i], g_alog[i]);
  g_h2[i] = fmaf(gs, faa_in[i], g_alog[i]);
  g_h3[i] = fmaf(gs, gbb_in[i], g_blog[i]);
}

// ---------------------------------------------------------------------------
// Fused MFMA + softmin tile pass. One block = one 128x128 tile of one cost
// slab; the tile is COMPUTED (never loaded): dot products via the
// round-9/10-verified MFMA fragment code, then the round-8-verified
// two-phase (max, sum) row-dir + col-dir partial softmin on the acc
// registers. v_row = (hr_j - yn_j*ie) + (-xn_i*ie) + dot*ie, analogous col.
// (C>=0 clamp dropped: only shifts near-zero C by fp16-dot noise ~4e-3.)
// Sym slabs (Cxx/Cyy): upper-triangle tiles; col-dir covers the mirror.
// ---------------------------------------------------------------------------
struct TPArgs {
  const half_t* Ar;     // row-entity fp16 vectors
  const half_t* Bc;     // col-entity fp16 vectors
  const float* nrow;    // 0.5*||row||^2
  const float* ncol;
  const float* hrow;    // h over cols (row-dir softmin weights)
  const float* hcol;    // h over rows (col-dir)
  float2* prow;         // [b][chunk][row]
  float2* pcol;
  int sym;
};

__global__ __launch_bounds__(256) void tile_pass(
    TPArgs T0, TPArgs T1, TPArgs T2, float inv_eps)
{
  TPArgs A = (blockIdx.z == 0) ? T0 : (blockIdx.z == 1) ? T1 : T2;
  int I, J;
  if (A.sym) {
    if (blockIdx.x >= 136) return;
    int rem = blockIdx.x, ii = 0;
    while (rem >= NCHK - ii) { rem -= NCHK - ii; ++ii; }   // uniform, <=16 iters
    I = ii; J = ii + rem;                                  // I <= J
  } else {
    I = blockIdx.x >> 4;
    J = blockIdx.x & 15;
  }
  const int b = blockIdx.y;
  const int t = threadIdx.x;
  const int w = t >> 6, lane = t & 63;
  const int m = lane & 15, quad = lane >> 4;
  const int i0 = I * TS, j0 = J * TS;
  const float ie = inv_eps;

  // ---- MFMA dot products (fragment layout HW-verified green, r9/r10) ----
  const half_t* Abase = A.Ar + ((size_t)b * NN + i0 + 32 * w + m) * DD + quad * 8;
  const half_t* Bbase = A.Bc + ((size_t)b * MM + j0 + m) * DD + quad * 8;

  f32x4 acc[2][8];
#pragma unroll
  for (int g = 0; g < 2; ++g)
#pragma unroll
    for (int c = 0; c < 8; ++c) acc[g][c] = (f32x4){0.f, 0.f, 0.f, 0.f};

#pragma unroll
  for (int s = 0; s < 2; ++s) {
    f16x8 a0 = *(const f16x8*)(Abase + s * 32);
    f16x8 a1 = *(const f16x8*)(Abase + (size_t)16 * DD + s * 32);
#pragma unroll
    for (int c = 0; c < 8; ++c) {
      f16x8 bf = *(const f16x8*)(Bbase + (size_t)(16 * c) * DD + s * 32);
      acc[0][c] = __builtin_amdgcn_mfma_f32_16x16x32_f16(a0, bf, acc[0][c], 0, 0, 0);
      acc[1][c] = __builtin_amdgcn_mfma_f32_16x16x32_f16(a1, bf, acc[1][c], 0, 0, 0);
    }
  }
  // acc[g][c][r] = dot(x_i, y_j): i = i0+32w+16g+4*quad+r, j = j0+16c+m.

  // ---- per-thread row/col constants ----
  float Aj[8], Bj[8];           // col j: Aj = hr_j - yn_j*ie ; Bj = -yn_j*ie
  float Ai[8], Bi[8];           // row i: Ai = hc_i - xn_i*ie ; Bi = -xn_i*ie
#pragma unroll
  for (int c = 0; c < 8; ++c) {
    int j = b * MM + j0 + 16 * c + m;
    float ynj = A.ncol[j];
    Bj[c] = -ynj * ie;
    Aj[c] = A.hrow[j] + Bj[c];
  }
#pragma unroll
  for (int g = 0; g < 2; ++g) {
    int ib = b * NN + i0 + 32 * w + 16 * g + 4 * quad;
    float4 xn4 = *(const float4*)(A.nrow + ib);
    float4 hc4 = *(const float4*)(A.hcol + ib);
    float xg[4] = {xn4.x, xn4.y, xn4.z, xn4.w};
    float hg[4] = {hc4.x, hc4.y, hc4.z, hc4.w};
#pragma unroll
    for (int r = 0; r < 4; ++r) {
      Bi[g * 4 + r] = -xg[r] * ie;
      Ai[g * 4 + r] = hg[r] + Bi[g * 4 + r];
    }
  }

  __shared__ float redR[TS][17], redC[TS][17];   // +1 pad vs bank conflicts
  __shared__ float rowM[TS], colM[TS];

  // ---- phase A: maxes (scale acc -> t in place) ----
  float rm[8], cm[8];
#pragma unroll
  for (int k = 0; k < 8; ++k) { rm[k] = -3.0e38f; cm[k] = -3.0e38f; }
#pragma unroll
  for (int g = 0; g < 2; ++g)
#pragma unroll
    for (int c = 0; c < 8; ++c) {
      f32x4 tv = acc[g][c];
#pragma unroll
      for (int r = 0; r < 4; ++r) {
        float tt = tv[r] * ie;
        tv[r] = tt;
        rm[g * 4 + r] = fmaxf(rm[g * 4 + r], tt + Bi[g * 4 + r] + Aj[c]);
        cm[c] = fmaxf(cm[c], tt + Ai[g * 4 + r] + Bj[c]);
      }
      acc[g][c] = tv;   // now holds dot*ie
    }
#pragma unroll
  for (int k = 0; k < 8; ++k)
    redR[32 * w + 16 * (k >> 2) + 4 * quad + (k & 3)][m] = rm[k];
#pragma unroll
  for (int c = 0; c < 8; ++c)
    redC[16 * c + m][w * 4 + quad] = cm[c];
  __syncthreads();
  if (t < TS) {
    float v = redR[t][0];
#pragma unroll
    for (int k = 1; k < 16; ++k) v = fmaxf(v, redR[t][k]);
    rowM[t] = v;
  } else {
    int tt = t - TS;
    float v = redC[tt][0];
#pragma unroll
    for (int k = 1; k < 16; ++k) v = fmaxf(v, redC[tt][k]);
    colM[tt] = v;
  }
  __syncthreads();

  float BR[8], CB[8];
#pragma unroll
  for (int k = 0; k < 8; ++k)
    BR[k] = Bi[k] - rowM[32 * w + 16 * (k >> 2) + 4 * quad + (k & 3)];
#pragma unroll
  for (int c = 0; c < 8; ++c)
    CB[c] = Bj[c] - colM[16 * c + m];

  // ---- phase B: sums ----
  float rs[8], cs[8];
#pragma unroll
  for (int k = 0; k < 8; ++k) { rs[k] = 0.f; cs[k] = 0.f; }
#pragma unroll
  for (int g = 0; g < 2; ++g)
#pragma unroll
    for (int c = 0; c < 8; ++c) {
      f32x4 tv = acc[g][c];
#pragma unroll
      for (int r = 0; r < 4; ++r) {
        rs[g * 4 + r] += __expf(tv[r] + BR[g * 4 + r] + Aj[c]);
        cs[c] += __expf(tv[r] + Ai[g * 4 + r] + CB[c]);
      }
    }
  __syncthreads();   // redR/redC reuse
#pragma unroll
  for (int k = 0; k < 8; ++k)
    redR[32 * w + 16 * (k >> 2) + 4 * quad + (k & 3)][m] = rs[k];
#pragma unroll
  for (int c = 0; c < 8; ++c)
    redC[16 * c + m][w * 4 + quad] = cs[c];
  __syncthreads();
  if (t < TS) {
    float s = 0.f;
#pragma unroll
    for (int k = 0; k < 16; ++k) s += redR[t][k];
    A.prow[((size_t)b * NCHK + J) * NN + I * TS + t] = make_float2(rowM[t], s);
  } else {
    int tt = t - TS;
    if (!(A.sym && I == J)) {   // diagonal col-dir duplicates row-dir: skip
      float s = 0.f;
#pragma unroll
      for (int k = 0; k < 16; ++k) s += redC[tt][k];
      A.pcol[((size_t)b * NCHK + I) * NN + J * TS + tt] = make_float2(colM[tt], s);
    }
  }
}

// ---------------------------------------------------------------------------
// merge 16 chunk-partials per row -> softmin + Jacobi update + next-h write.
// (verified rounds 8-10, unchanged)
// ---------------------------------------------------------------------------
struct MergeArgs {
  const float2* part;
  const float* fold;
  float* fout;
  const float* hbase;   // alog or blog
  float* hout;          // h vector consumed by the next tile_pass
};

__global__ __launch_bounds__(256) void merge4(
    MergeArgs M0, MergeArgs M1, MergeArgs M2, MergeArgs M3,
    float eps, float alpha, float beta, float nextgs)
{
  MergeArgs A = (blockIdx.z == 0) ? M0 : (blockIdx.z == 1) ? M1
              : (blockIdx.z == 2) ? M2 : M3;
  const int b = blockIdx.y;
  const int i = blockIdx.x * 256 + threadIdx.x;   // grid.x = NN/256
  float2 p[NCHK];
#pragma unroll
  for (int k = 0; k < NCHK; ++k)
    p[k] = A.part[((size_t)b * NCHK + k) * NN + i];
  float M = p[0].x;
#pragma unroll
  for (int k = 1; k < NCHK; ++k) M = fmaxf(M, p[k].x);
  float S = 0.f;
#pragma unroll
  for (int k = 0; k < NCHK; ++k) S += p[k].y * __expf(p[k].x - M);
  float ft = -eps * (M + __logf(S));
  int idx = b * NN + i;
  float fnew = alpha * A.fold[idx] + beta * ft;
  A.fout[idx] = fnew;
  A.hout[idx] = fmaf(nextgs, fnew, A.hbase[idx]);
}

// ---------------------------------------------------------------------------
// loss = mean_b [ sum_i w1*(fabf - faaf) + sum_j w2*(gbaf - gbbf) ]
// ---------------------------------------------------------------------------
__global__ __launch_bounds__(256) void loss_kernel(
    const float* __restrict__ w1, const float* __restrict__ w2,
    float* __restrict__ out)
{
  __shared__ float red[256];
  float acc = 0.f;
  for (int idx = threadIdx.x; idx < NB * NN; idx += 256) {
    acc += w1[idx] * (g_fab[2][idx] - g_faa[2][idx])
         + w2[idx] * (g_gba[2][idx] - g_gbb[2][idx]);
  }
  red[threadIdx.x] = acc;
  __syncthreads();
  for (int s = 128; s > 0; s >>= 1) {
    if (threadIdx.x < s) red[threadIdx.x] += red[threadIdx.x + s];
    __syncthreads();
  }
  if (threadIdx.x == 0) out[0] = red[0] * (1.0f / NB);
}

// ---------------------------------------------------------------------------
extern "C" void kernel_launch(void* const* d_in, const int* in_sizes, int n_in,
                              void* d_out, int out_size, void* d_ws, size_t ws_size,
                              hipStream_t stream)
{
  const float* x = (const float*)d_in[0];
  const float* y = (const float*)d_in[1];
  const float* w1 = (const float*)d_in[2];
  const float* w2 = (const float*)d_in[3];
  float* out = (float*)d_out;

  half_t *xh, *yh;
  float *xn, *yn, *h0, *h1, *h2, *h3, *fabp, *gbap, *faap, *gbbp, *alog, *blog;
  float2 *pfab, *pgba, *pfaa, *pgbb;
  hipGetSymbolAddress((void**)&xh, HIP_SYMBOL(g_xh));
  hipGetSymbolAddress((void**)&yh, HIP_SYMBOL(g_yh));
  hipGetSymbolAddress((void**)&xn, HIP_SYMBOL(g_xn));
  hipGetSymbolAddress((void**)&yn, HIP_SYMBOL(g_yn));
  hipGetSymbolAddress((void**)&h0, HIP_SYMBOL(g_h0));
  hipGetSymbolAddress((void**)&h1, HIP_SYMBOL(g_h1));
  hipGetSymbolAddress((void**)&h2, HIP_SYMBOL(g_h2));
  hipGetSymbolAddress((void**)&h3, HIP_SYMBOL(g_h3));
  hipGetSymbolAddress((void**)&fabp, HIP_SYMBOL(g_fab));
  hipGetSymbolAddress((void**)&gbap, HIP_SYMBOL(g_gba));
  hipGetSymbolAddress((void**)&faap, HIP_SYMBOL(g_faa));
  hipGetSymbolAddress((void**)&gbbp, HIP_SYMBOL(g_gbb));
  hipGetSymbolAddress((void**)&alog, HIP_SYMBOL(g_alog));
  hipGetSymbolAddress((void**)&blog, HIP_SYMBOL(g_blog));
  hipGetSymbolAddress((void**)&pfab, HIP_SYMBOL(g_pfab));
  hipGetSymbolAddress((void**)&pgba, HIP_SYMBOL(g_pgba));
  hipGetSymbolAddress((void**)&pfaa, HIP_SYMBOL(g_pfaa));
  hipGetSymbolAddress((void**)&pgbb, HIP_SYMBOL(g_pgbb));

  auto fab = [&](int s) { return fabp + (size_t)s * NB * NN; };
  auto gba = [&](int s) { return gbap + (size_t)s * NB * NN; };
  auto faa = [&](int s) { return faap + (size_t)s * NB * NN; };
  auto gbb = [&](int s) { return gbbp + (size_t)s * NB * NN; };

  // eps schedule (matches the Python double loop, then cast to fp32)
  float eps_list[32];
  int ne = 0;
  {
    double v = 64.0 * 64.0;
    double tgt = 0.05 * 0.05;
    while (v > tgt) { eps_list[ne++] = (float)v; v *= 0.25; }
    eps_list[ne++] = (float)tgt;   // ne == 12
  }

  prep_kernel<<<4096, 256, 0, stream>>>(x, y, w1, w2);

  dim3 tg(256, NB, 3);          // z: 0=Cxy(256 tiles), 1/2=Cxx/Cyy(tri 136)
  dim3 mg(NN / 256, NB, 4);     // z: potential

  // one iteration: tile_pass (h already in place) + merge4 (writes next h)
  auto launch_iter = [&](float eps, float alpha, float beta, float nextgs,
                         int in, int outsel) {
    float inv = 1.0f / eps;
    TPArgs T0 = {xh, yh, xn, yn, h0, h1, pfab, pgba, 0};
    TPArgs T1 = {xh, xh, xn, xn, h2, h2, pfaa, pfaa, 1};
    TPArgs T2 = {yh, yh, yn, yn, h3, h3, pgbb, pgbb, 1};
    tile_pass<<<tg, 256, 0, stream>>>(T0, T1, T2, inv);
    MergeArgs M0 = {pfab, fab(in), fab(outsel), alog, h1};
    MergeArgs M1 = {pgba, gba(in), gba(outsel), blog, h0};
    MergeArgs M2 = {pfaa, faa(in), faa(outsel), alog, h2};
    MergeArgs M3 = {pgbb, gbb(in), gbb(outsel), blog, h3};
    merge4<<<mg, 256, 0, stream>>>(M0, M1, M2, M3, eps, alpha, beta, nextgs);
  };

  // init at eps0: h = base log-weights (gs=0), alpha=0 -> no carry read;
  // its merge writes h for scan step k=0.
  hprep_kernel<<<64, 256, 0, stream>>>(fab(0), gba(0), faa(0), gbb(0), 0.f);
  launch_iter(eps_list[0], 0.f, 1.f, 1.0f / eps_list[0], 0, 0);

  // scan over the full eps list with 0.5-averaging (Jacobi, banks 0/1);
  // each merge writes h for the NEXT step (k+1, or the final extrapolation).
  int cur = 0;
  for (int k = 0; k < ne; ++k) {
    int nxt = 1 - cur;
    float nextgs = 1.0f / ((k < ne - 1) ? eps_list[k + 1] : eps_list[ne - 1]);
    launch_iter(eps_list[k], 0.5f, 0.5f, nextgs, cur, nxt);
    cur = nxt;
  }

  // final extrapolation at eps = blur^p (no averaging) -> bank 2
  launch_iter(eps_list[ne - 1], 0.f, 1.f, 0.f, cur, 2);

  loss_kernel<<<1, 256, 0, stream>>>(w1, w2, out);
}

// Round 12
// 1318.185 us; speedup vs baseline: 1.2554x; 1.2554x over previous
//
#include <hip/hip_runtime.h>

#define NB 8
#define NN 2048
#define MM 2048
#define DD 64
#define NMAT ((size_t)NN * (size_t)MM)
#define NCHK 16
#define TS 128

typedef _Float16 half_t;
typedef __attribute__((ext_vector_type(8))) _Float16 f16x8;
typedef __attribute__((ext_vector_type(4))) float f32x4;

// ---------------------------------------------------------------------------
// Static device scratch. No materialized cost matrices; all four softmins are
// row-direction passes with swapped operands (col-softmin over Cxy == row-
// softmin over Cyx == MFMA with (y,x)). x,y fp16 = 4 MB, L2-resident.
// ---------------------------------------------------------------------------
__device__ half_t g_xh[NB * NN * DD];           // fp16 copies for MFMA
__device__ half_t g_yh[NB * MM * DD];
// potential banks: [0]/[1] = carry double-buffer, [2] = final
__device__ float g_fab[3][NB * NN], g_gba[3][NB * NN];
__device__ float g_faa[3][NB * NN], g_gbb[3][NB * NN];
__device__ float g_alog[NB * NN], g_blog[NB * NN];
__device__ float g_xn[NB * NN], g_yn[NB * NN];
__device__ float g_h0[NB * MM], g_h1[NB * NN], g_h2[NB * NN], g_h3[NB * MM];
// chunked softmin partials (m,s): [b][chunk][row]
__device__ float2 g_pfab[NB * NCHK * NN];
__device__ float2 g_pgba[NB * NCHK * NN];
__device__ float2 g_pfaa[NB * NCHK * NN];
__device__ float2 g_pgbb[NB * NCHK * NN];

// ---------------------------------------------------------------------------
// prep: a_log/b_log = log(w), xn/yn = 0.5*||row||^2, and fp16 copies of x,y.
// ---------------------------------------------------------------------------
__global__ __launch_bounds__(256) void prep_kernel(
    const float* __restrict__ x, const float* __restrict__ y,
    const float* __restrict__ w1, const float* __restrict__ w2)
{
  int gid = blockIdx.x * 256 + threadIdx.x;
  if (gid < NB * NN) {
    g_alog[gid] = logf(w1[gid]);
    g_blog[gid] = logf(w2[gid]);
  }
  int lane = threadIdx.x & 63;
  int row = blockIdx.x * 4 + (threadIdx.x >> 6);   // grid 4096 -> rows 0..16383
  float xv = x[(size_t)row * DD + lane];
  float yv = y[(size_t)row * DD + lane];
  g_xh[(size_t)row * DD + lane] = (half_t)xv;
  g_yh[(size_t)row * DD + lane] = (half_t)yv;
  float sx = xv * xv;
  float sy = yv * yv;
#pragma unroll
  for (int off = 32; off > 0; off >>= 1) {
    sx += __shfl_down(sx, off);
    sy += __shfl_down(sy, off);
  }
  if (lane == 0) {
    g_xn[row] = 0.5f * sx;
    g_yn[row] = 0.5f * sy;
  }
}

// ---------------------------------------------------------------------------
// h-vector prep — used ONCE for the init step (gs = 0); subsequent h's are
// written by merge4.
// ---------------------------------------------------------------------------
__global__ __launch_bounds__(256) void hprep_kernel(
    const float* __restrict__ fab_in, const float* __restrict__ gba_in,
    const float* __restrict__ faa_in, const float* __restrict__ gbb_in,
    float gs)
{
  int i = blockIdx.x * 256 + threadIdx.x;   // grid 64 -> 16384
  g_h0[i] = fmaf(gs, gba_in[i], g_blog[i]);
  g_h1[i] = fmaf(gs, fab_in[i], g_alog[i]);
  g_h2[i] = fmaf(gs, faa_in[i], g_alog[i]);
  g_h3[i] = fmaf(gs, gbb_in[i], g_blog[i]);
}

// ---------------------------------------------------------------------------
// Row-direction fused MFMA+softmin pass. One block = one 128x128 tile of one
// of the 4 problems (blockIdx.z): rows are entity Ar, cols entity Bc.
// Wave w owns rows 32w..32w+31; the full 128-col reduction for each row is
// WAVE-LOCAL (cols = 16c + m: c in-thread, m = 16 contiguous lanes) -> all
// reductions are 4-step shfl_xor butterflies. No LDS, no barriers.
// v_ij = dot*ie + (h_j - yn_j*ie) + (-xn_i*ie); the row constant cancels in
// exp(v - max) and is added to the partial max only at the write.
// MFMA fragment layout: verified green rounds 9-11.
// ---------------------------------------------------------------------------
struct RPArgs {
  const half_t* Ar;     // row-entity fp16 vectors
  const half_t* Bc;     // col-entity fp16 vectors
  const float* nrow;    // 0.5*||row||^2 for row entities
  const float* ncol;    // for col entities
  const float* h;       // softmin weights over cols
  float2* pout;         // [b][chunkJ][row]
};

__global__ __launch_bounds__(256, 4) void row_pass(
    RPArgs P0, RPArgs P1, RPArgs P2, RPArgs P3, float ie)
{
  RPArgs A = (blockIdx.z == 0) ? P0 : (blockIdx.z == 1) ? P1
           : (blockIdx.z == 2) ? P2 : P3;
  const int b = blockIdx.y;
  const int I = blockIdx.x >> 4, J = blockIdx.x & 15;
  const int t = threadIdx.x;
  const int w = t >> 6, lane = t & 63;
  const int m = lane & 15, quad = lane >> 4;
  const int i0 = I * TS + 32 * w;   // wave's 32 rows
  const int j0 = J * TS;

  // ---- MFMA dot products (verified fragment code) ----
  const half_t* Abase = A.Ar + ((size_t)b * NN + i0 + m) * DD + quad * 8;
  const half_t* Bbase = A.Bc + ((size_t)b * MM + j0 + m) * DD + quad * 8;

  f32x4 acc[2][8];
#pragma unroll
  for (int g = 0; g < 2; ++g)
#pragma unroll
    for (int c = 0; c < 8; ++c) acc[g][c] = (f32x4){0.f, 0.f, 0.f, 0.f};

#pragma unroll
  for (int s = 0; s < 2; ++s) {
    f16x8 a0 = *(const f16x8*)(Abase + s * 32);
    f16x8 a1 = *(const f16x8*)(Abase + (size_t)16 * DD + s * 32);
#pragma unroll
    for (int c = 0; c < 8; ++c) {
      f16x8 bf = *(const f16x8*)(Bbase + (size_t)(16 * c) * DD + s * 32);
      acc[0][c] = __builtin_amdgcn_mfma_f32_16x16x32_f16(a0, bf, acc[0][c], 0, 0, 0);
      acc[1][c] = __builtin_amdgcn_mfma_f32_16x16x32_f16(a1, bf, acc[1][c], 0, 0, 0);
    }
  }
  // acc[g][c][r] = dot(row i, col j): i = i0+16g+4*quad+r, j = j0+16c+m.

  // col constants: ccst[c] = h_j - yn_j*ie
  float ccst[8];
#pragma unroll
  for (int c = 0; c < 8; ++c) {
    int j = b * MM + j0 + 16 * c + m;
    ccst[c] = fmaf(-ie, A.ncol[j], A.h[j]);
  }

  // phase A: per-row maxes over c (in-thread), then butterfly over m
  float mx[8];
#pragma unroll
  for (int k = 0; k < 8; ++k) mx[k] = -3.0e38f;
#pragma unroll
  for (int g = 0; g < 2; ++g)
#pragma unroll
    for (int c = 0; c < 8; ++c) {
      f32x4 tv = acc[g][c];
#pragma unroll
      for (int r = 0; r < 4; ++r) {
        float v = fmaf(tv[r], ie, ccst[c]);
        tv[r] = v;                               // acc now holds v (no rowconst)
        mx[g * 4 + r] = fmaxf(mx[g * 4 + r], v);
      }
      acc[g][c] = tv;
    }
#pragma unroll
  for (int mask = 1; mask < 16; mask <<= 1)
#pragma unroll
    for (int k = 0; k < 8; ++k)
      mx[k] = fmaxf(mx[k], __shfl_xor(mx[k], mask));

  // phase B: sums of exp(v - mx), butterfly over m
  float ss[8];
#pragma unroll
  for (int k = 0; k < 8; ++k) ss[k] = 0.f;
#pragma unroll
  for (int g = 0; g < 2; ++g)
#pragma unroll
    for (int c = 0; c < 8; ++c) {
      f32x4 tv = acc[g][c];
#pragma unroll
      for (int r = 0; r < 4; ++r)
        ss[g * 4 + r] += __expf(tv[r] - mx[g * 4 + r]);
    }
#pragma unroll
  for (int mask = 1; mask < 16; mask <<= 1)
#pragma unroll
    for (int k = 0; k < 8; ++k)
      ss[k] += __shfl_xor(ss[k], mask);

  // write: lane m<8 writes k=m; true partial max adds the row constant
  if (m < 8) {
    int k = m;
    int i = i0 + 16 * (k >> 2) + 4 * quad + (k & 3);
    float Mv = fmaf(-ie, A.nrow[b * NN + i], mx[k]);
    A.pout[((size_t)b * NCHK + J) * NN + i] = make_float2(Mv, ss[k]);
  }
}

// ---------------------------------------------------------------------------
// merge 16 chunk-partials per row -> softmin + Jacobi update + next-h write.
// (verified rounds 8-11, unchanged)
// ---------------------------------------------------------------------------
struct MergeArgs {
  const float2* part;
  const float* fold;
  float* fout;
  const float* hbase;   // alog or blog
  float* hout;          // h vector consumed by the next row_pass
};

__global__ __launch_bounds__(256) void merge4(
    MergeArgs M0, MergeArgs M1, MergeArgs M2, MergeArgs M3,
    float eps, float alpha, float beta, float nextgs)
{
  MergeArgs A = (blockIdx.z == 0) ? M0 : (blockIdx.z == 1) ? M1
              : (blockIdx.z == 2) ? M2 : M3;
  const int b = blockIdx.y;
  const int i = blockIdx.x * 256 + threadIdx.x;   // grid.x = NN/256
  float2 p[NCHK];
#pragma unroll
  for (int k = 0; k < NCHK; ++k)
    p[k] = A.part[((size_t)b * NCHK + k) * NN + i];
  float M = p[0].x;
#pragma unroll
  for (int k = 1; k < NCHK; ++k) M = fmaxf(M, p[k].x);
  float S = 0.f;
#pragma unroll
  for (int k = 0; k < NCHK; ++k) S += p[k].y * __expf(p[k].x - M);
  float ft = -eps * (M + __logf(S));
  int idx = b * NN + i;
  float fnew = alpha * A.fold[idx] + beta * ft;
  A.fout[idx] = fnew;
  A.hout[idx] = fmaf(nextgs, fnew, A.hbase[idx]);
}

// ---------------------------------------------------------------------------
// loss = mean_b [ sum_i w1*(fabf - faaf) + sum_j w2*(gbaf - gbbf) ]
// ---------------------------------------------------------------------------
__global__ __launch_bounds__(256) void loss_kernel(
    const float* __restrict__ w1, const float* __restrict__ w2,
    float* __restrict__ out)
{
  __shared__ float red[256];
  float acc = 0.f;
  for (int idx = threadIdx.x; idx < NB * NN; idx += 256) {
    acc += w1[idx] * (g_fab[2][idx] - g_faa[2][idx])
         + w2[idx] * (g_gba[2][idx] - g_gbb[2][idx]);
  }
  red[threadIdx.x] = acc;
  __syncthreads();
  for (int s = 128; s > 0; s >>= 1) {
    if (threadIdx.x < s) red[threadIdx.x] += red[threadIdx.x + s];
    __syncthreads();
  }
  if (threadIdx.x == 0) out[0] = red[0] * (1.0f / NB);
}

// ---------------------------------------------------------------------------
extern "C" void kernel_launch(void* const* d_in, const int* in_sizes, int n_in,
                              void* d_out, int out_size, void* d_ws, size_t ws_size,
                              hipStream_t stream)
{
  const float* x = (const float*)d_in[0];
  const float* y = (const float*)d_in[1];
  const float* w1 = (const float*)d_in[2];
  const float* w2 = (const float*)d_in[3];
  float* out = (float*)d_out;

  half_t *xh, *yh;
  float *xn, *yn, *h0, *h1, *h2, *h3, *fabp, *gbap, *faap, *gbbp, *alog, *blog;
  float2 *pfab, *pgba, *pfaa, *pgbb;
  hipGetSymbolAddress((void**)&xh, HIP_SYMBOL(g_xh));
  hipGetSymbolAddress((void**)&yh, HIP_SYMBOL(g_yh));
  hipGetSymbolAddress((void**)&xn, HIP_SYMBOL(g_xn));
  hipGetSymbolAddress((void**)&yn, HIP_SYMBOL(g_yn));
  hipGetSymbolAddress((void**)&h0, HIP_SYMBOL(g_h0));
  hipGetSymbolAddress((void**)&h1, HIP_SYMBOL(g_h1));
  hipGetSymbolAddress((void**)&h2, HIP_SYMBOL(g_h2));
  hipGetSymbolAddress((void**)&h3, HIP_SYMBOL(g_h3));
  hipGetSymbolAddress((void**)&fabp, HIP_SYMBOL(g_fab));
  hipGetSymbolAddress((void**)&gbap, HIP_SYMBOL(g_gba));
  hipGetSymbolAddress((void**)&faap, HIP_SYMBOL(g_faa));
  hipGetSymbolAddress((void**)&gbbp, HIP_SYMBOL(g_gbb));
  hipGetSymbolAddress((void**)&alog, HIP_SYMBOL(g_alog));
  hipGetSymbolAddress((void**)&blog, HIP_SYMBOL(g_blog));
  hipGetSymbolAddress((void**)&pfab, HIP_SYMBOL(g_pfab));
  hipGetSymbolAddress((void**)&pgba, HIP_SYMBOL(g_pgba));
  hipGetSymbolAddress((void**)&pfaa, HIP_SYMBOL(g_pfaa));
  hipGetSymbolAddress((void**)&pgbb, HIP_SYMBOL(g_pgbb));

  auto fab = [&](int s) { return fabp + (size_t)s * NB * NN; };
  auto gba = [&](int s) { return gbap + (size_t)s * NB * NN; };
  auto faa = [&](int s) { return faap + (size_t)s * NB * NN; };
  auto gbb = [&](int s) { return gbbp + (size_t)s * NB * NN; };

  // eps schedule (matches the Python double loop, then cast to fp32)
  float eps_list[32];
  int ne = 0;
  {
    double v = 64.0 * 64.0;
    double tgt = 0.05 * 0.05;
    while (v > tgt) { eps_list[ne++] = (float)v; v *= 0.25; }
    eps_list[ne++] = (float)tgt;   // ne == 12
  }

  prep_kernel<<<4096, 256, 0, stream>>>(x, y, w1, w2);

  dim3 tg(256, NB, 4);          // z: 0=fab(x,y) 1=gba(y,x) 2=faa(x,x) 3=gbb(y,y)
  dim3 mg(NN / 256, NB, 4);     // z: potential

  // one iteration: row_pass x4 (h already in place) + merge4 (writes next h)
  auto launch_iter = [&](float eps, float alpha, float beta, float nextgs,
                         int in, int outsel) {
    float inv = 1.0f / eps;
    RPArgs P0 = {xh, yh, xn, yn, h0, pfab};
    RPArgs P1 = {yh, xh, yn, xn, h1, pgba};
    RPArgs P2 = {xh, xh, xn, xn, h2, pfaa};
    RPArgs P3 = {yh, yh, yn, yn, h3, pgbb};
    row_pass<<<tg, 256, 0, stream>>>(P0, P1, P2, P3, inv);
    MergeArgs M0 = {pfab, fab(in), fab(outsel), alog, h1};
    MergeArgs M1 = {pgba, gba(in), gba(outsel), blog, h0};
    MergeArgs M2 = {pfaa, faa(in), faa(outsel), alog, h2};
    MergeArgs M3 = {pgbb, gbb(in), gbb(outsel), blog, h3};
    merge4<<<mg, 256, 0, stream>>>(M0, M1, M2, M3, eps, alpha, beta, nextgs);
  };

  // init at eps0: h = base log-weights (gs=0), alpha=0 -> no carry read;
  // its merge writes h for scan step k=0.
  hprep_kernel<<<64, 256, 0, stream>>>(fab(0), gba(0), faa(0), gbb(0), 0.f);
  launch_iter(eps_list[0], 0.f, 1.f, 1.0f / eps_list[0], 0, 0);

  // scan over the full eps list with 0.5-averaging (Jacobi, banks 0/1);
  // each merge writes h for the NEXT step (k+1, or the final extrapolation).
  int cur = 0;
  for (int k = 0; k < ne; ++k) {
    int nxt = 1 - cur;
    float nextgs = 1.0f / ((k < ne - 1) ? eps_list[k + 1] : eps_list[ne - 1]);
    launch_iter(eps_list[k], 0.5f, 0.5f, nextgs, cur, nxt);
    cur = nxt;
  }

  // final extrapolation at eps = blur^p (no averaging) -> bank 2
  launch_iter(eps_list[ne - 1], 0.f, 1.f, 0.f, cur, 2);

  loss_kernel<<<1, 256, 0, stream>>>(w1, w2, out);
}

// Round 13
// 787.170 us; speedup vs baseline: 2.1022x; 1.6746x over previous
//
#include <hip/hip_runtime.h>

#define NB 8
#define NN 2048
#define MM 2048
#define DD 64
#define NMAT ((size_t)NN * (size_t)MM)
#define NCHK 16
#define TS 128

// uint16 fixed-point encoding of C (verified exact: rounds 5-10 absmax 0.0)
#define CSCALE 320.0f
#define CDEC   (1.0f / CSCALE)

typedef _Float16 half_t;
typedef __attribute__((ext_vector_type(8))) _Float16 f16x8;
typedef __attribute__((ext_vector_type(4))) float f32x4;
typedef __attribute__((ext_vector_type(4))) unsigned int u32x4;

// ---------------------------------------------------------------------------
// Static device scratch. Three u16 cost slabs; sym slabs hold valid data only
// in upper-triangle 128-chunks (all tile_pass ever reads).
// ---------------------------------------------------------------------------
__device__ unsigned short g_C[3 * NB * NMAT];   // Cxy|Cxx|Cyy
__device__ half_t g_xh[NB * NN * DD];           // fp16 copies for MFMA
__device__ half_t g_yh[NB * MM * DD];
// potential banks: [0]/[1] = carry double-buffer, [2] = final
__device__ float g_fab[3][NB * NN], g_gba[3][NB * NN];
__device__ float g_faa[3][NB * NN], g_gbb[3][NB * NN];
__device__ float g_alog[NB * NN], g_blog[NB * NN];
__device__ float g_xn[NB * NN], g_yn[NB * NN];
__device__ float g_h0[NB * MM], g_h1[NB * NN], g_h2[NB * NN], g_h3[NB * MM];
// chunked softmin partials (m,s): [b][chunk][row]
__device__ float2 g_pfab[NB * NCHK * NN];
__device__ float2 g_pgba[NB * NCHK * NN];
__device__ float2 g_pfaa[NB * NCHK * NN];
__device__ float2 g_pgbb[NB * NCHK * NN];

// ---------------------------------------------------------------------------
// prep: a_log/b_log = log(w), xn/yn = 0.5*||row||^2, and fp16 copies of x,y.
// ---------------------------------------------------------------------------
__global__ __launch_bounds__(256) void prep_kernel(
    const float* __restrict__ x, const float* __restrict__ y,
    const float* __restrict__ w1, const float* __restrict__ w2)
{
  int gid = blockIdx.x * 256 + threadIdx.x;
  if (gid < NB * NN) {
    g_alog[gid] = logf(w1[gid]);
    g_blog[gid] = logf(w2[gid]);
  }
  int lane = threadIdx.x & 63;
  int row = blockIdx.x * 4 + (threadIdx.x >> 6);   // grid 4096 -> rows 0..16383
  float xv = x[(size_t)row * DD + lane];
  float yv = y[(size_t)row * DD + lane];
  g_xh[(size_t)row * DD + lane] = (half_t)xv;
  g_yh[(size_t)row * DD + lane] = (half_t)yv;
  float sx = xv * xv;
  float sy = yv * yv;
#pragma unroll
  for (int off = 32; off > 0; off >>= 1) {
    sx += __shfl_down(sx, off);
    sy += __shfl_down(sy, off);
  }
  if (lane == 0) {
    g_xn[row] = 0.5f * sx;
    g_yn[row] = 0.5f * sy;
  }
}

// ---------------------------------------------------------------------------
// MFMA cost build (verified r10): 128x128 tile per block; wave w = rows
// 32w..32w+31 (2 row-groups x 8 col-groups, 32 MFMAs). z = slab*8 + b;
// slab 0 = all 256 tiles, slabs 1/2 = 136 upper-tri tiles.
// C stores are NON-TEMPORAL: C (201 MB) is write-once, read later in full-
// slab streams >> L2, so L2 allocation on store is pure overhead.
// ---------------------------------------------------------------------------
__global__ __launch_bounds__(256) void cost_mfma()
{
  const int slab = blockIdx.z >> 3;
  const int b = blockIdx.z & 7;
  int I, J;
  if (slab) {
    if (blockIdx.x >= 136) return;
    int rem = blockIdx.x, ii = 0;
    while (rem >= NCHK - ii) { rem -= NCHK - ii; ++ii; }   // uniform, <=16 iters
    I = ii; J = ii + rem;                                  // I <= J
  } else {
    I = blockIdx.x >> 4;
    J = blockIdx.x & 15;
  }

  const half_t* Ah = (slab == 2) ? g_yh : g_xh;
  const half_t* Bh = (slab == 0) ? g_yh : ((slab == 1) ? g_xh : g_yh);
  const float* na = (slab == 2) ? g_yn : g_xn;
  const float* nbp = (slab == 0) ? g_yn : ((slab == 1) ? g_xn : g_yn);
  unsigned short* Cout = g_C + (size_t)slab * NB * NMAT + (size_t)b * NMAT;

  const int t = threadIdx.x;
  const int w = t >> 6, lane = t & 63;
  const int m = lane & 15, quad = lane >> 4;
  const int i0 = I * TS, j0 = J * TS;

  const half_t* Abase = Ah + ((size_t)b * NN + i0 + 32 * w + m) * DD + quad * 8;
  const half_t* Bbase = Bh + ((size_t)b * MM + j0 + m) * DD + quad * 8;

  f32x4 acc[2][8];
#pragma unroll
  for (int g = 0; g < 2; ++g)
#pragma unroll
    for (int c = 0; c < 8; ++c) acc[g][c] = (f32x4){0.f, 0.f, 0.f, 0.f};

#pragma unroll
  for (int s = 0; s < 2; ++s) {
    f16x8 a0 = *(const f16x8*)(Abase + s * 32);
    f16x8 a1 = *(const f16x8*)(Abase + (size_t)16 * DD + s * 32);
#pragma unroll
    for (int c = 0; c < 8; ++c) {
      f16x8 bf = *(const f16x8*)(Bbase + (size_t)(16 * c) * DD + s * 32);
      acc[0][c] = __builtin_amdgcn_mfma_f32_16x16x32_f16(a0, bf, acc[0][c], 0, 0, 0);
      acc[1][c] = __builtin_amdgcn_mfma_f32_16x16x32_f16(a1, bf, acc[1][c], 0, 0, 0);
    }
  }

  __shared__ unsigned short tile[TS * TS];   // 32 KB
  float4 xr[2];
#pragma unroll
  for (int g = 0; g < 2; ++g)
    xr[g] = *(const float4*)(na + b * NN + i0 + 32 * w + 16 * g + 4 * quad);
#pragma unroll
  for (int c = 0; c < 8; ++c) {
    float yv = nbp[b * MM + j0 + 16 * c + m];
#pragma unroll
    for (int g = 0; g < 2; ++g) {
      float xg[4] = {xr[g].x, xr[g].y, xr[g].z, xr[g].w};
#pragma unroll
      for (int r = 0; r < 4; ++r) {
        float cv = fmaxf(xg[r] + yv - acc[g][c][r], 0.f);
        unsigned int u = __float2uint_rn(fminf(cv * CSCALE, 65535.f));
        tile[(32 * w + 16 * g + 4 * quad + r) * TS + 16 * c + m] = (unsigned short)u;
      }
    }
  }
  __syncthreads();

  const u32x4* tl = (const u32x4*)tile;   // 2048 vec4 in the tile
#pragma unroll
  for (int p = 0; p < 8; ++p) {
    int u = p * 256 + t;
    int row = u >> 4, c8 = (u & 15) * 8;
    u32x4 val = tl[u];
    __builtin_nontemporal_store(val, (u32x4*)(Cout + (size_t)(i0 + row) * MM + j0 + c8));
  }
}

// ---------------------------------------------------------------------------
// h-vector prep — used ONCE for the init step (gs = 0); subsequent h's are
// written by merge4.
// ---------------------------------------------------------------------------
__global__ __launch_bounds__(256) void hprep_kernel(
    const float* __restrict__ fab_in, const float* __restrict__ gba_in,
    const float* __restrict__ faa_in, const float* __restrict__ gbb_in,
    float gs)
{
  int i = blockIdx.x * 256 + threadIdx.x;   // grid 64 -> 16384
  g_h0[i] = fmaf(gs, gba_in[i], g_blog[i]);
  g_h1[i] = fmaf(gs, fab_in[i], g_alog[i]);
  g_h2[i] = fmaf(gs, faa_in[i], g_alog[i]);
  g_h3[i] = fmaf(gs, gbb_in[i], g_blog[i]);
}

// ---------------------------------------------------------------------------
// Unified tile-partial softmin pass (verified rounds 8-10). Tile held in
// registers; C loads NON-TEMPORAL (read-once stream, no reuse — keep L2
// clean for x/y/h). Row-dir + col-dir (m,s) partials, two-phase max/sum.
// ---------------------------------------------------------------------------
struct TileArgs {
  const unsigned short* C;
  const float* hrow;
  const float* hcol;
  float2* prow;   // [b][chunk][row]
  float2* pcol;
  int sym;        // 1 => triangular tile enumeration (136 tiles)
};

__global__ __launch_bounds__(256) void tile_pass(
    TileArgs T0, TileArgs T1, TileArgs T2, float inv_eps)
{
  TileArgs A = (blockIdx.z == 0) ? T0 : (blockIdx.z == 1) ? T1 : T2;
  int I, J;
  if (A.sym) {
    if (blockIdx.x >= 136) return;
    int rem = blockIdx.x, ii = 0;
    while (rem >= NCHK - ii) { rem -= NCHK - ii; ++ii; }   // uniform, <=16 iters
    I = ii; J = ii + rem;                                  // I <= J
  } else {
    I = blockIdx.x >> 4;
    J = blockIdx.x & 15;
  }
  const int b = blockIdx.y;
  const int t = threadIdx.x;
  const int ctr = t & 15;   // col-group: tile cols ctr*8 .. +7
  const int rtr = t >> 4;   // row-group: tile rows rtr*8 .. +7
  const float csneg = -inv_eps * CDEC;

  const unsigned short* Cb = A.C + (size_t)b * NMAT
                           + (size_t)(I * TS) * MM + J * TS;

  float hr[8], hc[8];
  {
    const float* hrp = A.hrow + (size_t)b * MM + J * TS + ctr * 8;
    const float* hcp = A.hcol + (size_t)b * MM + I * TS + rtr * 8;
#pragma unroll
    for (int k = 0; k < 8; ++k) { hr[k] = hrp[k]; hc[k] = hcp[k]; }
  }

  // tile chunk -> registers (single non-temporal global read)
  u32x4 cu[8];
#pragma unroll
  for (int r8 = 0; r8 < 8; ++r8)
    cu[r8] = __builtin_nontemporal_load(
        (const u32x4*)(Cb + (size_t)(rtr * 8 + r8) * MM + ctr * 8));

  __shared__ float redR[TS][17], redC[TS][17];   // +1 pad vs bank conflicts
  __shared__ float rowM[TS], colM[TS];

  // ---- phase A: maxes (unpack from registers) ----
  float rm[8], cm[8];
#pragma unroll
  for (int k = 0; k < 8; ++k) { rm[k] = -3.0e38f; cm[k] = -3.0e38f; }
#pragma unroll
  for (int r8 = 0; r8 < 8; ++r8) {
    float base[8];
    base[0] = (float)(cu[r8].x & 0xffff) * csneg;
    base[1] = (float)(cu[r8].x >> 16)    * csneg;
    base[2] = (float)(cu[r8].y & 0xffff) * csneg;
    base[3] = (float)(cu[r8].y >> 16)    * csneg;
    base[4] = (float)(cu[r8].z & 0xffff) * csneg;
    base[5] = (float)(cu[r8].z >> 16)    * csneg;
    base[6] = (float)(cu[r8].w & 0xffff) * csneg;
    base[7] = (float)(cu[r8].w >> 16)    * csneg;
#pragma unroll
    for (int c8 = 0; c8 < 8; ++c8) {
      rm[r8] = fmaxf(rm[r8], hr[c8] + base[c8]);
      cm[c8] = fmaxf(cm[c8], hc[r8] + base[c8]);
    }
  }
#pragma unroll
  for (int r8 = 0; r8 < 8; ++r8) redR[rtr * 8 + r8][ctr] = rm[r8];
#pragma unroll
  for (int c8 = 0; c8 < 8; ++c8) redC[ctr * 8 + c8][rtr] = cm[c8];
  __syncthreads();
  if (t < TS) {
    float m = redR[t][0];
#pragma unroll
    for (int k = 1; k < 16; ++k) m = fmaxf(m, redR[t][k]);
    rowM[t] = m;
  } else {
    int tt = t - TS;
    float m = redC[tt][0];
#pragma unroll
    for (int k = 1; k < 16; ++k) m = fmaxf(m, redC[tt][k]);
    colM[tt] = m;
  }
  __syncthreads();

  float rmv[8], cmv[8];
#pragma unroll
  for (int k = 0; k < 8; ++k) {
    rmv[k] = rowM[rtr * 8 + k];
    cmv[k] = colM[ctr * 8 + k];
  }

  // ---- phase B: sums (unpack same registers again — no global re-read) ----
  float rs[8], cs[8];
#pragma unroll
  for (int k = 0; k < 8; ++k) { rs[k] = 0.f; cs[k] = 0.f; }
#pragma unroll
  for (int r8 = 0; r8 < 8; ++r8) {
    float base[8];
    base[0] = (float)(cu[r8].x & 0xffff) * csneg;
    base[1] = (float)(cu[r8].x >> 16)    * csneg;
    base[2] = (float)(cu[r8].y & 0xffff) * csneg;
    base[3] = (float)(cu[r8].y >> 16)    * csneg;
    base[4] = (float)(cu[r8].z & 0xffff) * csneg;
    base[5] = (float)(cu[r8].z >> 16)    * csneg;
    base[6] = (float)(cu[r8].w & 0xffff) * csneg;
    base[7] = (float)(cu[r8].w >> 16)    * csneg;
#pragma unroll
    for (int c8 = 0; c8 < 8; ++c8) {
      rs[r8] += __expf(hr[c8] + base[c8] - rmv[r8]);
      cs[c8] += __expf(hc[r8] + base[c8] - cmv[c8]);
    }
  }
#pragma unroll
  for (int r8 = 0; r8 < 8; ++r8) redR[rtr * 8 + r8][ctr] = rs[r8];
#pragma unroll
  for (int c8 = 0; c8 < 8; ++c8) redC[ctr * 8 + c8][rtr] = cs[c8];
  __syncthreads();
  if (t < TS) {
    float s = 0.f;
#pragma unroll
    for (int k = 0; k < 16; ++k) s += redR[t][k];
    A.prow[((size_t)b * NCHK + J) * NN + I * TS + t] = make_float2(rowM[t], s);
  } else {
    int tt = t - TS;
    if (!(A.sym && I == J)) {   // diagonal col-dir duplicates row-dir: skip
      float s = 0.f;
#pragma unroll
      for (int k = 0; k < 16; ++k) s += redC[tt][k];
      A.pcol[((size_t)b * NCHK + I) * NN + J * TS + tt] = make_float2(colM[tt], s);
    }
  }
}

// ---------------------------------------------------------------------------
// merge 16 chunk-partials per row -> softmin + Jacobi update + next-h write.
// (verified rounds 8-10, unchanged)
// ---------------------------------------------------------------------------
struct MergeArgs {
  const float2* part;
  const float* fold;
  float* fout;
  const float* hbase;   // alog or blog
  float* hout;          // h vector consumed by the next tile_pass
};

__global__ __launch_bounds__(256) void merge4(
    MergeArgs M0, MergeArgs M1, MergeArgs M2, MergeArgs M3,
    float eps, float alpha, float beta, float nextgs)
{
  MergeArgs A = (blockIdx.z == 0) ? M0 : (blockIdx.z == 1) ? M1
              : (blockIdx.z == 2) ? M2 : M3;
  const int b = blockIdx.y;
  const int i = blockIdx.x * 256 + threadIdx.x;   // grid.x = NN/256
  float2 p[NCHK];
#pragma unroll
  for (int k = 0; k < NCHK; ++k)
    p[k] = A.part[((size_t)b * NCHK + k) * NN + i];
  float M = p[0].x;
#pragma unroll
  for (int k = 1; k < NCHK; ++k) M = fmaxf(M, p[k].x);
  float S = 0.f;
#pragma unroll
  for (int k = 0; k < NCHK; ++k) S += p[k].y * __expf(p[k].x - M);
  float ft = -eps * (M + __logf(S));
  int idx = b * NN + i;
  float fnew = alpha * A.fold[idx] + beta * ft;
  A.fout[idx] = fnew;
  A.hout[idx] = fmaf(nextgs, fnew, A.hbase[idx]);
}

// ---------------------------------------------------------------------------
// loss = mean_b [ sum_i w1*(fabf - faaf) + sum_j w2*(gbaf - gbbf) ]
// ---------------------------------------------------------------------------
__global__ __launch_bounds__(256) void loss_kernel(
    const float* __restrict__ w1, const float* __restrict__ w2,
    float* __restrict__ out)
{
  __shared__ float red[256];
  float acc = 0.f;
  for (int idx = threadIdx.x; idx < NB * NN; idx += 256) {
    acc += w1[idx] * (g_fab[2][idx] - g_faa[2][idx])
         + w2[idx] * (g_gba[2][idx] - g_gbb[2][idx]);
  }
  red[threadIdx.x] = acc;
  __syncthreads();
  for (int s = 128; s > 0; s >>= 1) {
    if (threadIdx.x < s) red[threadIdx.x] += red[threadIdx.x + s];
    __syncthreads();
  }
  if (threadIdx.x == 0) out[0] = red[0] * (1.0f / NB);
}

// ---------------------------------------------------------------------------
extern "C" void kernel_launch(void* const* d_in, const int* in_sizes, int n_in,
                              void* d_out, int out_size, void* d_ws, size_t ws_size,
                              hipStream_t stream)
{
  const float* x = (const float*)d_in[0];
  const float* y = (const float*)d_in[1];
  const float* w1 = (const float*)d_in[2];
  const float* w2 = (const float*)d_in[3];
  float* out = (float*)d_out;

  unsigned short* Cbase;
  hipGetSymbolAddress((void**)&Cbase, HIP_SYMBOL(g_C));
  unsigned short* Cxy = Cbase + 0ull * NB * NMAT;
  unsigned short* Cxx = Cbase + 1ull * NB * NMAT;
  unsigned short* Cyy = Cbase + 2ull * NB * NMAT;
  float *h0, *h1, *h2, *h3, *fabp, *gbap, *faap, *gbbp, *alog, *blog;
  float2 *pfab, *pgba, *pfaa, *pgbb;
  hipGetSymbolAddress((void**)&h0, HIP_SYMBOL(g_h0));
  hipGetSymbolAddress((void**)&h1, HIP_SYMBOL(g_h1));
  hipGetSymbolAddress((void**)&h2, HIP_SYMBOL(g_h2));
  hipGetSymbolAddress((void**)&h3, HIP_SYMBOL(g_h3));
  hipGetSymbolAddress((void**)&fabp, HIP_SYMBOL(g_fab));
  hipGetSymbolAddress((void**)&gbap, HIP_SYMBOL(g_gba));
  hipGetSymbolAddress((void**)&faap, HIP_SYMBOL(g_faa));
  hipGetSymbolAddress((void**)&gbbp, HIP_SYMBOL(g_gbb));
  hipGetSymbolAddress((void**)&alog, HIP_SYMBOL(g_alog));
  hipGetSymbolAddress((void**)&blog, HIP_SYMBOL(g_blog));
  hipGetSymbolAddress((void**)&pfab, HIP_SYMBOL(g_pfab));
  hipGetSymbolAddress((void**)&pgba, HIP_SYMBOL(g_pgba));
  hipGetSymbolAddress((void**)&pfaa, HIP_SYMBOL(g_pfaa));
  hipGetSymbolAddress((void**)&pgbb, HIP_SYMBOL(g_pgbb));

  auto fab = [&](int s) { return fabp + (size_t)s * NB * NN; };
  auto gba = [&](int s) { return gbap + (size_t)s * NB * NN; };
  auto faa = [&](int s) { return faap + (size_t)s * NB * NN; };
  auto gbb = [&](int s) { return gbbp + (size_t)s * NB * NN; };

  // eps schedule (matches the Python double loop, then cast to fp32)
  float eps_list[32];
  int ne = 0;
  {
    double v = 64.0 * 64.0;
    double tgt = 0.05 * 0.05;
    while (v > tgt) { eps_list[ne++] = (float)v; v *= 0.25; }
    eps_list[ne++] = (float)tgt;   // ne == 12
  }

  prep_kernel<<<4096, 256, 0, stream>>>(x, y, w1, w2);

  // all three cost slabs in one dispatch; 128x128 tiles; sym = tri only
  cost_mfma<<<dim3(256, 1, 24), 256, 0, stream>>>();

  dim3 tg(256, NB, 3);          // z: 0=Cxy(256 tiles), 1/2=Cxx/Cyy(tri 136)
  dim3 mg(NN / 256, NB, 4);     // z: potential

  // one iteration: tile_pass (h already in place) + merge4 (writes next h)
  auto launch_iter = [&](float eps, float alpha, float beta, float nextgs,
                         int in, int outsel) {
    float inv = 1.0f / eps;
    TileArgs T0 = {Cxy, h0, h1, pfab, pgba, 0};
    TileArgs T1 = {Cxx, h2, h2, pfaa, pfaa, 1};
    TileArgs T2 = {Cyy, h3, h3, pgbb, pgbb, 1};
    tile_pass<<<tg, 256, 0, stream>>>(T0, T1, T2, inv);
    MergeArgs M0 = {pfab, fab(in), fab(outsel), alog, h1};
    MergeArgs M1 = {pgba, gba(in), gba(outsel), blog, h0};
    MergeArgs M2 = {pfaa, faa(in), faa(outsel), alog, h2};
    MergeArgs M3 = {pgbb, gbb(in), gbb(outsel), blog, h3};
    merge4<<<mg, 256, 0, stream>>>(M0, M1, M2, M3, eps, alpha, beta, nextgs);
  };

  // init at eps0: h = base log-weights (gs=0), alpha=0 -> no carry read;
  // its merge writes h for scan step k=0.
  hprep_kernel<<<64, 256, 0, stream>>>(fab(0), gba(0), faa(0), gbb(0), 0.f);
  launch_iter(eps_list[0], 0.f, 1.f, 1.0f / eps_list[0], 0, 0);

  // scan over the full eps list with 0.5-averaging (Jacobi, banks 0/1);
  // each merge writes h for the NEXT step (k+1, or the final extrapolation).
  int cur = 0;
  for (int k = 0; k < ne; ++k) {
    int nxt = 1 - cur;
    float nextgs = 1.0f / ((k < ne - 1) ? eps_list[k + 1] : eps_list[ne - 1]);
    launch_iter(eps_list[k], 0.5f, 0.5f, nextgs, cur, nxt);
    cur = nxt;
  }

  // final extrapolation at eps = blur^p (no averaging) -> bank 2
  launch_iter(eps_list[ne - 1], 0.f, 1.f, 0.f, cur, 2);

  loss_kernel<<<1, 256, 0, stream>>>(w1, w2, out);
}

// Round 14
// 717.531 us; speedup vs baseline: 2.3062x; 1.0971x over previous
//
#include <hip/hip_runtime.h>

#define NB 8
#define NN 2048
#define MM 2048
#define DD 64
#define NMAT ((size_t)NN * (size_t)MM)
#define NCHK 16
#define TS 128

// uint16 fixed-point encoding of C (verified exact: rounds 5-10 absmax 0.0)
#define CSCALE 320.0f
#define CDEC   (1.0f / CSCALE)
#define LOG2E  1.4426950408889634f
#define LN2    0.6931471805599453f

typedef _Float16 half_t;
typedef __attribute__((ext_vector_type(8))) _Float16 f16x8;
typedef __attribute__((ext_vector_type(4))) float f32x4;

// ---------------------------------------------------------------------------
// Static device scratch. Three u16 cost slabs (201 MB, mostly L3-resident);
// sym slabs valid only in upper-triangle 128-chunks.
// ---------------------------------------------------------------------------
__device__ unsigned short g_C[3 * NB * NMAT];   // Cxy|Cxx|Cyy
__device__ half_t g_xh[NB * NN * DD];           // fp16 copies for MFMA
__device__ half_t g_yh[NB * MM * DD];
// potential banks: [0]/[1] = carry double-buffer, [2] = final
__device__ float g_fab[3][NB * NN], g_gba[3][NB * NN];
__device__ float g_faa[3][NB * NN], g_gbb[3][NB * NN];
__device__ float g_alog[NB * NN], g_blog[NB * NN];
__device__ float g_xn[NB * NN], g_yn[NB * NN];
__device__ float g_h0[NB * MM], g_h1[NB * NN], g_h2[NB * NN], g_h3[NB * MM];
// chunked softmin partials (m2, s): m2 is in BASE-2 log units
__device__ float2 g_pfab[NB * NCHK * NN];
__device__ float2 g_pgba[NB * NCHK * NN];
__device__ float2 g_pfaa[NB * NCHK * NN];
__device__ float2 g_pgbb[NB * NCHK * NN];

// ---------------------------------------------------------------------------
// prep: a_log/b_log = log(w), xn/yn = 0.5*||row||^2, and fp16 copies of x,y.
// ---------------------------------------------------------------------------
__global__ __launch_bounds__(256) void prep_kernel(
    const float* __restrict__ x, const float* __restrict__ y,
    const float* __restrict__ w1, const float* __restrict__ w2)
{
  int gid = blockIdx.x * 256 + threadIdx.x;
  if (gid < NB * NN) {
    g_alog[gid] = logf(w1[gid]);
    g_blog[gid] = logf(w2[gid]);
  }
  int lane = threadIdx.x & 63;
  int row = blockIdx.x * 4 + (threadIdx.x >> 6);   // grid 4096 -> rows 0..16383
  float xv = x[(size_t)row * DD + lane];
  float yv = y[(size_t)row * DD + lane];
  g_xh[(size_t)row * DD + lane] = (half_t)xv;
  g_yh[(size_t)row * DD + lane] = (half_t)yv;
  float sx = xv * xv;
  float sy = yv * yv;
#pragma unroll
  for (int off = 32; off > 0; off >>= 1) {
    sx += __shfl_down(sx, off);
    sy += __shfl_down(sy, off);
  }
  if (lane == 0) {
    g_xn[row] = 0.5f * sx;
    g_yn[row] = 0.5f * sy;
  }
}

// ---------------------------------------------------------------------------
// MFMA cost build (verified r10, plain stores — NT regressed in r13).
// 128x128 tile per block; z = slab*8 + b; slab 0 = 256 tiles, 1/2 = tri 136.
// ---------------------------------------------------------------------------
__global__ __launch_bounds__(256) void cost_mfma()
{
  const int slab = blockIdx.z >> 3;
  const int b = blockIdx.z & 7;
  int I, J;
  if (slab) {
    if (blockIdx.x >= 136) return;
    int rem = blockIdx.x, ii = 0;
    while (rem >= NCHK - ii) { rem -= NCHK - ii; ++ii; }   // uniform, <=16 iters
    I = ii; J = ii + rem;                                  // I <= J
  } else {
    I = blockIdx.x >> 4;
    J = blockIdx.x & 15;
  }

  const half_t* Ah = (slab == 2) ? g_yh : g_xh;
  const half_t* Bh = (slab == 0) ? g_yh : ((slab == 1) ? g_xh : g_yh);
  const float* na = (slab == 2) ? g_yn : g_xn;
  const float* nbp = (slab == 0) ? g_yn : ((slab == 1) ? g_xn : g_yn);
  unsigned short* Cout = g_C + (size_t)slab * NB * NMAT + (size_t)b * NMAT;

  const int t = threadIdx.x;
  const int w = t >> 6, lane = t & 63;
  const int m = lane & 15, quad = lane >> 4;
  const int i0 = I * TS, j0 = J * TS;

  const half_t* Abase = Ah + ((size_t)b * NN + i0 + 32 * w + m) * DD + quad * 8;
  const half_t* Bbase = Bh + ((size_t)b * MM + j0 + m) * DD + quad * 8;

  f32x4 acc[2][8];
#pragma unroll
  for (int g = 0; g < 2; ++g)
#pragma unroll
    for (int c = 0; c < 8; ++c) acc[g][c] = (f32x4){0.f, 0.f, 0.f, 0.f};

#pragma unroll
  for (int s = 0; s < 2; ++s) {
    f16x8 a0 = *(const f16x8*)(Abase + s * 32);
    f16x8 a1 = *(const f16x8*)(Abase + (size_t)16 * DD + s * 32);
#pragma unroll
    for (int c = 0; c < 8; ++c) {
      f16x8 bf = *(const f16x8*)(Bbase + (size_t)(16 * c) * DD + s * 32);
      acc[0][c] = __builtin_amdgcn_mfma_f32_16x16x32_f16(a0, bf, acc[0][c], 0, 0, 0);
      acc[1][c] = __builtin_amdgcn_mfma_f32_16x16x32_f16(a1, bf, acc[1][c], 0, 0, 0);
    }
  }

  __shared__ unsigned short tile[TS * TS];   // 32 KB
  float4 xr[2];
#pragma unroll
  for (int g = 0; g < 2; ++g)
    xr[g] = *(const float4*)(na + b * NN + i0 + 32 * w + 16 * g + 4 * quad);
#pragma unroll
  for (int c = 0; c < 8; ++c) {
    float yv = nbp[b * MM + j0 + 16 * c + m];
#pragma unroll
    for (int g = 0; g < 2; ++g) {
      float xg[4] = {xr[g].x, xr[g].y, xr[g].z, xr[g].w};
#pragma unroll
      for (int r = 0; r < 4; ++r) {
        float cv = fmaxf(xg[r] + yv - acc[g][c][r], 0.f);
        unsigned int u = __float2uint_rn(fminf(cv * CSCALE, 65535.f));
        tile[(32 * w + 16 * g + 4 * quad + r) * TS + 16 * c + m] = (unsigned short)u;
      }
    }
  }
  __syncthreads();

  const uint4* tl = (const uint4*)tile;   // 2048 uint4 in the tile
#pragma unroll
  for (int p = 0; p < 8; ++p) {
    int u = p * 256 + t;
    int row = u >> 4, c8 = (u & 15) * 8;
    *(uint4*)(Cout + (size_t)(i0 + row) * MM + j0 + c8) = tl[u];
  }
}

// ---------------------------------------------------------------------------
// h-vector prep — used ONCE for the init step (gs = 0); subsequent h's are
// written by merge4. h stays in NATURAL log units.
// ---------------------------------------------------------------------------
__global__ __launch_bounds__(256) void hprep_kernel(
    const float* __restrict__ fab_in, const float* __restrict__ gba_in,
    const float* __restrict__ faa_in, const float* __restrict__ gbb_in,
    float gs)
{
  int i = blockIdx.x * 256 + threadIdx.x;   // grid 64 -> 16384
  g_h0[i] = fmaf(gs, gba_in[i], g_blog[i]);
  g_h1[i] = fmaf(gs, fab_in[i], g_alog[i]);
  g_h2[i] = fmaf(gs, faa_in[i], g_alog[i]);
  g_h3[i] = fmaf(gs, gbb_in[i], g_blog[i]);
}

// ---------------------------------------------------------------------------
// Unified tile-partial softmin pass (verified structure, r8-r10), with:
//  - BASE-2 exponent domain (h pre-scaled by log2e in regs; bare v_exp_f32)
//  - row-direction reductions INTRA-WAVE (4-step shfl_xor over ctr=lane&15)
//  - col-direction via LDS (halved LDS footprint: 9.2 KB)
// Partials (m2, s): m2 in base-2 units; merge4 converts back via ln2.
// ---------------------------------------------------------------------------
struct TileArgs {
  const unsigned short* C;
  const float* hrow;
  const float* hcol;
  float2* prow;   // [b][chunk][row]
  float2* pcol;
  int sym;        // 1 => triangular tile enumeration (136 tiles)
};

__global__ __launch_bounds__(256) void tile_pass(
    TileArgs T0, TileArgs T1, TileArgs T2, float inv_eps)
{
  TileArgs A = (blockIdx.z == 0) ? T0 : (blockIdx.z == 1) ? T1 : T2;
  int I, J;
  if (A.sym) {
    if (blockIdx.x >= 136) return;
    int rem = blockIdx.x, ii = 0;
    while (rem >= NCHK - ii) { rem -= NCHK - ii; ++ii; }   // uniform, <=16 iters
    I = ii; J = ii + rem;                                  // I <= J
  } else {
    I = blockIdx.x >> 4;
    J = blockIdx.x & 15;
  }
  const int b = blockIdx.y;
  const int t = threadIdx.x;
  const int ctr = t & 15;   // col-group: tile cols ctr*8 .. +7 (intra-wave!)
  const int rtr = t >> 4;   // row-group: tile rows rtr*8 .. +7
  const float cs2 = -inv_eps * CDEC * LOG2E;   // base-2 C coefficient

  const unsigned short* Cb = A.C + (size_t)b * NMAT
                           + (size_t)(I * TS) * MM + J * TS;

  float hr2[8], hc2[8];
  {
    const float* hrp = A.hrow + (size_t)b * MM + J * TS + ctr * 8;
    const float* hcp = A.hcol + (size_t)b * MM + I * TS + rtr * 8;
#pragma unroll
    for (int k = 0; k < 8; ++k) {
      hr2[k] = hrp[k] * LOG2E;
      hc2[k] = hcp[k] * LOG2E;
    }
  }

  // tile chunk -> registers (single global read; L3-resident stream)
  uint4 cu[8];
#pragma unroll
  for (int r8 = 0; r8 < 8; ++r8)
    cu[r8] = *(const uint4*)(Cb + (size_t)(rtr * 8 + r8) * MM + ctr * 8);

  __shared__ float redC[TS][17];   // +1 pad vs bank conflicts
  __shared__ float colM[TS];

  // ---- phase A: maxes ----
  float rm[8], cm[8];
#pragma unroll
  for (int k = 0; k < 8; ++k) { rm[k] = -3.0e38f; cm[k] = -3.0e38f; }
#pragma unroll
  for (int r8 = 0; r8 < 8; ++r8) {
    float u[8];
    u[0] = (float)(cu[r8].x & 0xffff);
    u[1] = (float)(cu[r8].x >> 16);
    u[2] = (float)(cu[r8].y & 0xffff);
    u[3] = (float)(cu[r8].y >> 16);
    u[4] = (float)(cu[r8].z & 0xffff);
    u[5] = (float)(cu[r8].z >> 16);
    u[6] = (float)(cu[r8].w & 0xffff);
    u[7] = (float)(cu[r8].w >> 16);
#pragma unroll
    for (int c8 = 0; c8 < 8; ++c8) {
      rm[r8] = fmaxf(rm[r8], fmaf(u[c8], cs2, hr2[c8]));
      cm[c8] = fmaxf(cm[c8], fmaf(u[c8], cs2, hc2[r8]));
    }
  }
  // row maxes: intra-wave butterfly over ctr (masks 1..8 stay in 16-lane group)
#pragma unroll
  for (int mask = 1; mask < 16; mask <<= 1)
#pragma unroll
    for (int k = 0; k < 8; ++k)
      rm[k] = fmaxf(rm[k], __shfl_xor(rm[k], mask));
  // col maxes: LDS across waves
#pragma unroll
  for (int c8 = 0; c8 < 8; ++c8) redC[ctr * 8 + c8][rtr] = cm[c8];
  __syncthreads();
  if (t < TS) {
    float m = redC[t][0];
#pragma unroll
    for (int k = 1; k < 16; ++k) m = fmaxf(m, redC[t][k]);
    colM[t] = m;
  }
  __syncthreads();
  float cmv[8];
#pragma unroll
  for (int c8 = 0; c8 < 8; ++c8) cmv[c8] = colM[ctr * 8 + c8];

  // ---- phase B: sums (recompute v from registers; bare v_exp_f32) ----
  float rs[8], cs[8];
#pragma unroll
  for (int k = 0; k < 8; ++k) { rs[k] = 0.f; cs[k] = 0.f; }
#pragma unroll
  for (int r8 = 0; r8 < 8; ++r8) {
    float u[8];
    u[0] = (float)(cu[r8].x & 0xffff);
    u[1] = (float)(cu[r8].x >> 16);
    u[2] = (float)(cu[r8].y & 0xffff);
    u[3] = (float)(cu[r8].y >> 16);
    u[4] = (float)(cu[r8].z & 0xffff);
    u[5] = (float)(cu[r8].z >> 16);
    u[6] = (float)(cu[r8].w & 0xffff);
    u[7] = (float)(cu[r8].w >> 16);
#pragma unroll
    for (int c8 = 0; c8 < 8; ++c8) {
      rs[r8] += __builtin_amdgcn_exp2f(fmaf(u[c8], cs2, hr2[c8]) - rm[r8]);
      cs[c8] += __builtin_amdgcn_exp2f(fmaf(u[c8], cs2, hc2[r8]) - cmv[c8]);
    }
  }
  // row sums: butterfly; lanes ctr<8 write row rtr*8+ctr
#pragma unroll
  for (int mask = 1; mask < 16; mask <<= 1)
#pragma unroll
    for (int k = 0; k < 8; ++k)
      rs[k] += __shfl_xor(rs[k], mask);
  if (ctr < 8) {
    A.prow[((size_t)b * NCHK + J) * NN + I * TS + rtr * 8 + ctr]
        = make_float2(rm[ctr], rs[ctr]);
  }
  // col sums: LDS (safe to overwrite redC — all threads past the colM sync)
  __syncthreads();
#pragma unroll
  for (int c8 = 0; c8 < 8; ++c8) redC[ctr * 8 + c8][rtr] = cs[c8];
  __syncthreads();
  if (t < TS && !(A.sym && I == J)) {   // diagonal col-dir duplicates row-dir
    float s = 0.f;
#pragma unroll
    for (int k = 0; k < 16; ++k) s += redC[t][k];
    A.pcol[((size_t)b * NCHK + I) * NN + J * TS + t] = make_float2(colM[t], s);
  }
}

// ---------------------------------------------------------------------------
// merge 16 chunk-partials per row (BASE-2 partials) -> softmin + Jacobi
// update + next-h write.  ft = -eps * ln2 * (M2 + log2(S)).
// ---------------------------------------------------------------------------
struct MergeArgs {
  const float2* part;
  const float* fold;
  float* fout;
  const float* hbase;   // alog or blog
  float* hout;          // h vector consumed by the next tile_pass
};

__global__ __launch_bounds__(256) void merge4(
    MergeArgs M0, MergeArgs M1, MergeArgs M2, MergeArgs M3,
    float eps, float alpha, float beta, float nextgs)
{
  MergeArgs A = (blockIdx.z == 0) ? M0 : (blockIdx.z == 1) ? M1
              : (blockIdx.z == 2) ? M2 : M3;
  const int b = blockIdx.y;
  const int i = blockIdx.x * 256 + threadIdx.x;   // grid.x = NN/256
  float2 p[NCHK];
#pragma unroll
  for (int k = 0; k < NCHK; ++k)
    p[k] = A.part[((size_t)b * NCHK + k) * NN + i];
  float M = p[0].x;
#pragma unroll
  for (int k = 1; k < NCHK; ++k) M = fmaxf(M, p[k].x);
  float S = 0.f;
#pragma unroll
  for (int k = 0; k < NCHK; ++k)
    S += p[k].y * __builtin_amdgcn_exp2f(p[k].x - M);
  float ft = -eps * LN2 * (M + __builtin_amdgcn_logf(S));
  int idx = b * NN + i;
  float fnew = alpha * A.fold[idx] + beta * ft;
  A.fout[idx] = fnew;
  A.hout[idx] = fmaf(nextgs, fnew, A.hbase[idx]);
}

// ---------------------------------------------------------------------------
// loss = mean_b [ sum_i w1*(fabf - faaf) + sum_j w2*(gbaf - gbbf) ]
// ---------------------------------------------------------------------------
__global__ __launch_bounds__(256) void loss_kernel(
    const float* __restrict__ w1, const float* __restrict__ w2,
    float* __restrict__ out)
{
  __shared__ float red[256];
  float acc = 0.f;
  for (int idx = threadIdx.x; idx < NB * NN; idx += 256) {
    acc += w1[idx] * (g_fab[2][idx] - g_faa[2][idx])
         + w2[idx] * (g_gba[2][idx] - g_gbb[2][idx]);
  }
  red[threadIdx.x] = acc;
  __syncthreads();
  for (int s = 128; s > 0; s >>= 1) {
    if (threadIdx.x < s) red[threadIdx.x] += red[threadIdx.x + s];
    __syncthreads();
  }
  if (threadIdx.x == 0) out[0] = red[0] * (1.0f / NB);
}

// ---------------------------------------------------------------------------
extern "C" void kernel_launch(void* const* d_in, const int* in_sizes, int n_in,
                              void* d_out, int out_size, void* d_ws, size_t ws_size,
                              hipStream_t stream)
{
  const float* x = (const float*)d_in[0];
  const float* y = (const float*)d_in[1];
  const float* w1 = (const float*)d_in[2];
  const float* w2 = (const float*)d_in[3];
  float* out = (float*)d_out;

  unsigned short* Cbase;
  hipGetSymbolAddress((void**)&Cbase, HIP_SYMBOL(g_C));
  unsigned short* Cxy = Cbase + 0ull * NB * NMAT;
  unsigned short* Cxx = Cbase + 1ull * NB * NMAT;
  unsigned short* Cyy = Cbase + 2ull * NB * NMAT;
  float *h0, *h1, *h2, *h3, *fabp, *gbap, *faap, *gbbp, *alog, *blog;
  float2 *pfab, *pgba, *pfaa, *pgbb;
  hipGetSymbolAddress((void**)&h0, HIP_SYMBOL(g_h0));
  hipGetSymbolAddress((void**)&h1, HIP_SYMBOL(g_h1));
  hipGetSymbolAddress((void**)&h2, HIP_SYMBOL(g_h2));
  hipGetSymbolAddress((void**)&h3, HIP_SYMBOL(g_h3));
  hipGetSymbolAddress((void**)&fabp, HIP_SYMBOL(g_fab));
  hipGetSymbolAddress((void**)&gbap, HIP_SYMBOL(g_gba));
  hipGetSymbolAddress((void**)&faap, HIP_SYMBOL(g_faa));
  hipGetSymbolAddress((void**)&gbbp, HIP_SYMBOL(g_gbb));
  hipGetSymbolAddress((void**)&alog, HIP_SYMBOL(g_alog));
  hipGetSymbolAddress((void**)&blog, HIP_SYMBOL(g_blog));
  hipGetSymbolAddress((void**)&pfab, HIP_SYMBOL(g_pfab));
  hipGetSymbolAddress((void**)&pgba, HIP_SYMBOL(g_pgba));
  hipGetSymbolAddress((void**)&pfaa, HIP_SYMBOL(g_pfaa));
  hipGetSymbolAddress((void**)&pgbb, HIP_SYMBOL(g_pgbb));

  auto fab = [&](int s) { return fabp + (size_t)s * NB * NN; };
  auto gba = [&](int s) { return gbap + (size_t)s * NB * NN; };
  auto faa = [&](int s) { return faap + (size_t)s * NB * NN; };
  auto gbb = [&](int s) { return gbbp + (size_t)s * NB * NN; };

  // eps schedule (matches the Python double loop, then cast to fp32)
  float eps_list[32];
  int ne = 0;
  {
    double v = 64.0 * 64.0;
    double tgt = 0.05 * 0.05;
    while (v > tgt) { eps_list[ne++] = (float)v; v *= 0.25; }
    eps_list[ne++] = (float)tgt;   // ne == 12
  }

  prep_kernel<<<4096, 256, 0, stream>>>(x, y, w1, w2);

  // all three cost slabs in one dispatch; 128x128 tiles; sym = tri only
  cost_mfma<<<dim3(256, 1, 24), 256, 0, stream>>>();

  dim3 tg(256, NB, 3);          // z: 0=Cxy(256 tiles), 1/2=Cxx/Cyy(tri 136)
  dim3 mg(NN / 256, NB, 4);     // z: potential

  // one iteration: tile_pass (h already in place) + merge4 (writes next h)
  auto launch_iter = [&](float eps, float alpha, float beta, float nextgs,
                         int in, int outsel) {
    float inv = 1.0f / eps;
    TileArgs T0 = {Cxy, h0, h1, pfab, pgba, 0};
    TileArgs T1 = {Cxx, h2, h2, pfaa, pfaa, 1};
    TileArgs T2 = {Cyy, h3, h3, pgbb, pgbb, 1};
    tile_pass<<<tg, 256, 0, stream>>>(T0, T1, T2, inv);
    MergeArgs M0 = {pfab, fab(in), fab(outsel), alog, h1};
    MergeArgs M1 = {pgba, gba(in), gba(outsel), blog, h0};
    MergeArgs M2 = {pfaa, faa(in), faa(outsel), alog, h2};
    MergeArgs M3 = {pgbb, gbb(in), gbb(outsel), blog, h3};
    merge4<<<mg, 256, 0, stream>>>(M0, M1, M2, M3, eps, alpha, beta, nextgs);
  };

  // init at eps0: h = base log-weights (gs=0), alpha=0 -> no carry read;
  // its merge writes h for scan step k=0.
  hprep_kernel<<<64, 256, 0, stream>>>(fab(0), gba(0), faa(0), gbb(0), 0.f);
  launch_iter(eps_list[0], 0.f, 1.f, 1.0f / eps_list[0], 0, 0);

  // scan over the full eps list with 0.5-averaging (Jacobi, banks 0/1);
  // each merge writes h for the NEXT step (k+1, or the final extrapolation).
  int cur = 0;
  for (int k = 0; k < ne; ++k) {
    int nxt = 1 - cur;
    float nextgs = 1.0f / ((k < ne - 1) ? eps_list[k + 1] : eps_list[ne - 1]);
    launch_iter(eps_list[k], 0.5f, 0.5f, nextgs, cur, nxt);
    cur = nxt;
  }

  // final extrapolation at eps = blur^p (no averaging) -> bank 2
  launch_iter(eps_list[ne - 1], 0.f, 1.f, 0.f, cur, 2);

  loss_kernel<<<1, 256, 0, stream>>>(w1, w2, out);
}